// Round 17
// baseline (23.080 us; speedup 1.0000x reference)
//
#include <hip/hip_runtime.h>
#include <math.h>

// Problem constants
#define BINS   256
#define NPAIR  24        // B*C = 8*3
#define NPIX   16384     // 128*128
#define SPLIT  16        // blocks per (tensor,channel)
#define NBLK   (48 * SPLIT)   // 768 blocks = 3/CU

#define DELTA    0.003921568859f           // 1/255 (bin pitch)
// exp2-folded constants
#define NK2      -7213.475204f             // -5000 * log2(e)
#define A2K2     56.57627611f              // (10000/255) * log2(e)
#define B2K2     0.11093398f               // 5000*DELTA^2 * log2(e)
#define RHO1     0.85745468f               // rho   = exp(-2*5000*DELTA^2)
#define RHO3     0.63042510f               // rho^3
#define RHO4     0.54056079f               // rho^4
#define INV_NORM 39.894228040143274f       // 1/(sigma*sqrt(2*pi))

typedef float v2f __attribute__((ext_vector_type(2)));

// Instruction-count-pinned packed f32 ops (VOP3P). R16 post-mortem: all of
// {occupancy, ILP} null while measured time is ~3x the source-level issue
// model -> suspect <2 x float> scalarization/codegen bloat. Force v_pk_*.
__device__ __forceinline__ v2f pkmul(v2f a, v2f b) {
  v2f d;
  asm("v_pk_mul_f32 %0, %1, %2" : "=v"(d) : "v"(a), "v"(b));
  return d;
}
__device__ __forceinline__ v2f pkadd(v2f a, v2f b) {
  v2f d;
  asm("v_pk_add_f32 %0, %1, %2" : "=v"(d) : "v"(a), "v"(b));
  return d;
}

// ---------------------------------------------------------------------------
// Kernel 1: soft histogram, register-gather, 16 bins/lane, paired recurrence,
// 2 pixels/round, asm-pinned pk core + explicit ds_read prefetch.
// ---------------------------------------------------------------------------
__global__ __launch_bounds__(256) void hist_kernel(
    const float* __restrict__ targ, const float* __restrict__ pred,
    float* __restrict__ g_part) {
  __shared__ float h[4][4][BINS];   // [wave][subgroup][bin] = 16 KiB
  __shared__ float pxs[1024 + 8];   // pixel slab (+8 pad: last prefetch)

  const int t = threadIdx.x, lane = t & 63, wv = t >> 6;
  const int g = lane >> 4, lsub = lane & 15;
  const int pg = blockIdx.x >> 4;            // 0..47
  const int split = blockIdx.x & (SPLIT - 1);
  const int chan = (pg < NPAIR) ? pg : pg - NPAIR;
  const float* __restrict__ src = (pg < NPAIR) ? targ : pred;

  // stage 1024 pixels: 256 threads x float4 (coalesced)
  reinterpret_cast<float4*>(pxs)[t] =
      reinterpret_cast<const float4*>(src + chan * NPIX + split * 1024)[t];
  __syncthreads();

  const float c0 = (float)(16 * lsub) * DELTA;  // lane's first bin center
  const v2f RHO13 = {RHO1, RHO3};
  const v2f RHO44 = {RHO4, RHO4};

  v2f acc[8];
  #pragma unroll
  for (int i = 0; i < 8; ++i) acc[i] = (v2f){0.f, 0.f};

  // pointer-walk + 1-round-ahead register prefetch of the 2 broadcasts
  const float* pw = &pxs[wv * 256 + g];
  float xA = pw[0], xB = pw[4];

  #pragma unroll 4
  for (int r = 0; r < 32; ++r) {
    pw += 8;
    const float xAn = pw[0];     // next round (pad junk on r=31, dead)
    const float xBn = pw[4];

    const float dA = xA - c0;
    const float dB = xB - c0;
    const float w0A = __builtin_amdgcn_exp2f(NK2 * dA * dA);
    const float w0B = __builtin_amdgcn_exp2f(NK2 * dB * dB);
    const float q0A = __builtin_amdgcn_exp2f(A2K2 * dA - B2K2);
    const float q0B = __builtin_amdgcn_exp2f(A2K2 * dB - B2K2);

    v2f wA; wA.x = w0A; wA.y = w0A * q0A;
    v2f wB; wB.x = w0B; wB.y = w0B * q0B;
    v2f mA = pkmul((v2f){q0A * q0A, q0A * q0A}, RHO13);
    v2f mB = pkmul((v2f){q0B * q0B, q0B * q0B}, RHO13);
    acc[0] = pkadd(acc[0], pkadd(wA, wB));
    #pragma unroll
    for (int i = 1; i < 8; ++i) {
      wA = pkmul(wA, mA); wB = pkmul(wB, mB);
      mA = pkmul(mA, RHO44); mB = pkmul(mB, RHO44);
      acc[i] = pkadd(acc[i], pkadd(wA, wB));
    }
    xA = xAn; xB = xBn;
  }

  // block combine: 16 (wave,subgroup) partials -> one 256-bin block partial
  #pragma unroll
  for (int i = 0; i < 8; i += 2)
    reinterpret_cast<float4*>(&h[wv][g][16 * lsub + 2 * i])[0] =
        make_float4(acc[i].x, acc[i].y, acc[i + 1].x, acc[i + 1].y);
  __syncthreads();

  float s = 0.f;
  #pragma unroll
  for (int w2 = 0; w2 < 4; ++w2)
    #pragma unroll
    for (int g2 = 0; g2 < 4; ++g2) s += h[w2][g2][t];
  g_part[blockIdx.x * BINS + t] = s;          // blockIdx = pg*SPLIT+split
}

// ---------------------------------------------------------------------------
// Reductions
// ---------------------------------------------------------------------------
__device__ __forceinline__ float wave_allsum(float v) {
  #pragma unroll
  for (int off = 32; off > 0; off >>= 1) v += __shfl_xor(v, off, 64);
  return v;
}
__device__ __forceinline__ float block_sum(float v, float* red, int lane, int wv) {
  v = wave_allsum(v);
  __syncthreads();
  if (lane == 0) red[wv] = v;
  __syncthreads();
  return red[0] + red[1] + red[2] + red[3];
}

// ---------------------------------------------------------------------------
// Kernel 2: per-pair KL + fused final mean (R13 pattern, proven).
// ---------------------------------------------------------------------------
__global__ __launch_bounds__(256) void klfused_kernel(
    const float* __restrict__ g_part, unsigned int* __restrict__ fl1,
    unsigned int* __restrict__ fl2, float* __restrict__ out) {
  const int t = threadIdx.x, lane = t & 63, wv = t >> 6;
  const int p = blockIdx.x;

  if (p < NPAIR) {
    __shared__ float red[4];
    float ht = 0.f, hq = 0.f;
    #pragma unroll
    for (int s = 0; s < SPLIT; ++s) {
      ht += g_part[(p * SPLIT + s) * BINS + t];
      hq += g_part[((NPAIR + p) * SPLIT + s) * BINS + t];
    }
    ht *= INV_NORM;
    hq *= INV_NORM;

    const float st = block_sum(ht, red, lane, wv);
    const float sq = block_sum(hq, red, lane, wv);
    const float P = ht * __builtin_amdgcn_rcpf(st + 1e-10f) + 1e-10f;
    const float Q = hq * __builtin_amdgcn_rcpf(sq + 1e-10f) + 1e-10f;
    const float kl = block_sum(P * __logf(P / Q), red, lane, wv);
    if (t == 0) {
      const unsigned int b = __float_as_uint(kl);
      __hip_atomic_store(&fl1[p], b, __ATOMIC_RELEASE, __HIP_MEMORY_SCOPE_AGENT);
      __hip_atomic_store(&fl2[p], ~b, __ATOMIC_RELEASE, __HIP_MEMORY_SCOPE_AGENT);
    }
  } else {
    // finisher block: wave 0 only
    if (t >= 64) return;
    float v = 0.f;
    if (lane < NPAIR) {
      unsigned int a, b;
      do {
        a = __hip_atomic_load(&fl1[lane], __ATOMIC_ACQUIRE, __HIP_MEMORY_SCOPE_AGENT);
        b = __hip_atomic_load(&fl2[lane], __ATOMIC_ACQUIRE, __HIP_MEMORY_SCOPE_AGENT);
      } while (b != ~a);
      v = __uint_as_float(a);
    }
    v = wave_allsum(v);
    if (lane == 0) out[0] = v * (1.0f / NPAIR);
  }
}

// ---------------------------------------------------------------------------
extern "C" void kernel_launch(void* const* d_in, const int* in_sizes, int n_in,
                              void* d_out, int out_size, void* d_ws, size_t ws_size,
                              hipStream_t stream) {
  const float* targ = (const float*)d_in[0];
  const float* pred = (const float*)d_in[1];
  float* g_part = (float*)d_ws;                       // 768*256 f32 = 768 KiB
  unsigned int* fl1 = (unsigned int*)(g_part + NBLK * BINS);  // 24 words
  unsigned int* fl2 = fl1 + NPAIR;                            // 24 words
  float* out = (float*)d_out;

  hist_kernel<<<dim3(NBLK), dim3(256), 0, stream>>>(targ, pred, g_part);
  klfused_kernel<<<dim3(NPAIR + 1), dim3(256), 0, stream>>>(g_part, fl1, fl2, out);
}

// Round 18
// 22.031 us; speedup vs baseline: 1.0476x; 1.0476x over previous
//
#include <hip/hip_runtime.h>
#include <math.h>

// Problem constants
#define BINS   256
#define NPAIR  24        // B*C = 8*3
#define NPIX   16384     // 128*128
#define SPLIT  16        // blocks per (tensor,channel)
#define NBLK   (48 * SPLIT)   // 768 blocks

#define DELTA    0.003921568859f           // 1/255 (bin pitch)
// exp2-folded constants
#define NK2      -7213.475204f             // -5000 * log2(e)
#define A2K2     56.57627611f              // (10000/255) * log2(e)
#define B2K2     0.11093398f               // 5000*DELTA^2 * log2(e)
#define RHO1     0.85745468f               // rho   = exp(-2*5000*DELTA^2)
#define RHO3     0.63042510f               // rho^3
#define RHO4     0.54056079f               // rho^4
#define INV_NORM 39.894228040143274f       // 1/(sigma*sqrt(2*pi))

typedef float v2f __attribute__((ext_vector_type(2)));

// ---------------------------------------------------------------------------
// Kernel 1: soft histogram, register-gather, 16 bins/lane, paired recurrence,
// 2 pixels/round (exact R16 body). R18 delta: __launch_bounds__(256,4).
// Hypothesis: unbounded VGPR (>128) put us at 8 waves/CU (2 blocks/CU) —
// explaining the ILP-null (R16), the asm regression (R17), and the 2.5x gap
// vs the issue model. Cap at 128 VGPR -> 16 waves/CU = 4 blocks/CU.
// ---------------------------------------------------------------------------
__global__ __launch_bounds__(256, 4) void hist_kernel(
    const float* __restrict__ targ, const float* __restrict__ pred,
    float* __restrict__ g_part) {
  __shared__ float h[4][4][BINS];   // [wave][subgroup][bin] = 16 KiB
  __shared__ float pxs[1024];       // block's pixel slab

  const int t = threadIdx.x, lane = t & 63, wv = t >> 6;
  const int g = lane >> 4, lsub = lane & 15;
  const int pg = blockIdx.x >> 4;            // 0..47
  const int split = blockIdx.x & (SPLIT - 1);
  const int chan = (pg < NPAIR) ? pg : pg - NPAIR;
  const float* __restrict__ src = (pg < NPAIR) ? targ : pred;

  // stage 1024 pixels: 256 threads x float4 (coalesced, ds_write_b128)
  reinterpret_cast<float4*>(pxs)[t] =
      reinterpret_cast<const float4*>(src + chan * NPIX + split * 1024)[t];
  __syncthreads();

  const float c0 = (float)(16 * lsub) * DELTA;  // lane's first bin center
  const v2f RHO13 = {RHO1, RHO3};
  const v2f RHO44 = {RHO4, RHO4};

  v2f acc[8];
  #pragma unroll
  for (int i = 0; i < 8; ++i) acc[i] = (v2f){0.f, 0.f};

  #pragma unroll 2
  for (int r = 0; r < 32; ++r) {
    // subgroup g's two pixels this round (uniform per 16-lane subgroup)
    const float xA = pxs[wv * 256 + 8 * r + g];
    const float xB = pxs[wv * 256 + 8 * r + 4 + g];

    const float dA = xA - c0;
    const float dB = xB - c0;
    const float w0A = __builtin_amdgcn_exp2f(NK2 * dA * dA);
    const float w0B = __builtin_amdgcn_exp2f(NK2 * dB * dB);
    const float q0A = __builtin_amdgcn_exp2f(A2K2 * dA - B2K2);
    const float q0B = __builtin_amdgcn_exp2f(A2K2 * dB - B2K2);

    v2f wA; wA.x = w0A; wA.y = w0A * q0A;
    v2f wB; wB.x = w0B; wB.y = w0B * q0B;
    v2f mA = (q0A * q0A) * RHO13;
    v2f mB = (q0B * q0B) * RHO13;
    acc[0] += wA + wB;
    #pragma unroll
    for (int i = 1; i < 8; ++i) {
      wA *= mA; wB *= mB;      // two independent chains
      mA *= RHO44; mB *= RHO44;
      acc[i] += wA + wB;
    }
  }

  // block combine: 16 (wave,subgroup) partials -> one 256-bin block partial
  #pragma unroll
  for (int i = 0; i < 8; i += 2)
    reinterpret_cast<float4*>(&h[wv][g][16 * lsub + 2 * i])[0] =
        make_float4(acc[i].x, acc[i].y, acc[i + 1].x, acc[i + 1].y);
  __syncthreads();

  float s = 0.f;
  #pragma unroll
  for (int w2 = 0; w2 < 4; ++w2)
    #pragma unroll
    for (int g2 = 0; g2 < 4; ++g2) s += h[w2][g2][t];
  g_part[blockIdx.x * BINS + t] = s;          // blockIdx = pg*SPLIT+split
}

// ---------------------------------------------------------------------------
// Reductions
// ---------------------------------------------------------------------------
__device__ __forceinline__ float wave_allsum(float v) {
  #pragma unroll
  for (int off = 32; off > 0; off >>= 1) v += __shfl_xor(v, off, 64);
  return v;
}
__device__ __forceinline__ float block_sum(float v, float* red, int lane, int wv) {
  v = wave_allsum(v);
  __syncthreads();
  if (lane == 0) red[wv] = v;
  __syncthreads();
  return red[0] + red[1] + red[2] + red[3];
}

// ---------------------------------------------------------------------------
// Kernel 2: per-pair KL + fused final mean (R13/R16 pattern, proven).
// Blocks 0..23: pair KL, publish (bits, ~bits) release stores.
// Block 24: acquire-spin until fl2[p]==~fl1[p] for all p, write mean.
// Poison-safe (0xAA fails complement check); replay-safe (deterministic
// values are bit-identical across replays).
// ---------------------------------------------------------------------------
__global__ __launch_bounds__(256) void klfused_kernel(
    const float* __restrict__ g_part, unsigned int* __restrict__ fl1,
    unsigned int* __restrict__ fl2, float* __restrict__ out) {
  const int t = threadIdx.x, lane = t & 63, wv = t >> 6;
  const int p = blockIdx.x;

  if (p < NPAIR) {
    __shared__ float red[4];
    float ht = 0.f, hq = 0.f;
    #pragma unroll
    for (int s = 0; s < SPLIT; ++s) {
      ht += g_part[(p * SPLIT + s) * BINS + t];
      hq += g_part[((NPAIR + p) * SPLIT + s) * BINS + t];
    }
    ht *= INV_NORM;
    hq *= INV_NORM;

    const float st = block_sum(ht, red, lane, wv);
    const float sq = block_sum(hq, red, lane, wv);
    const float P = ht / (st + 1e-10f) + 1e-10f;
    const float Q = hq / (sq + 1e-10f) + 1e-10f;
    const float kl = block_sum(P * __logf(P / Q), red, lane, wv);
    if (t == 0) {
      const unsigned int b = __float_as_uint(kl);
      __hip_atomic_store(&fl1[p], b, __ATOMIC_RELEASE, __HIP_MEMORY_SCOPE_AGENT);
      __hip_atomic_store(&fl2[p], ~b, __ATOMIC_RELEASE, __HIP_MEMORY_SCOPE_AGENT);
    }
  } else {
    // finisher block: wave 0 only
    if (t >= 64) return;
    float v = 0.f;
    if (lane < NPAIR) {
      unsigned int a, b;
      do {
        a = __hip_atomic_load(&fl1[lane], __ATOMIC_ACQUIRE, __HIP_MEMORY_SCOPE_AGENT);
        b = __hip_atomic_load(&fl2[lane], __ATOMIC_ACQUIRE, __HIP_MEMORY_SCOPE_AGENT);
      } while (b != ~a);
      v = __uint_as_float(a);
    }
    v = wave_allsum(v);
    if (lane == 0) out[0] = v * (1.0f / NPAIR);
  }
}

// ---------------------------------------------------------------------------
extern "C" void kernel_launch(void* const* d_in, const int* in_sizes, int n_in,
                              void* d_out, int out_size, void* d_ws, size_t ws_size,
                              hipStream_t stream) {
  const float* targ = (const float*)d_in[0];
  const float* pred = (const float*)d_in[1];
  float* g_part = (float*)d_ws;                       // 768*256 f32 = 768 KiB
  unsigned int* fl1 = (unsigned int*)(g_part + NBLK * BINS);  // 24 words
  unsigned int* fl2 = fl1 + NPAIR;                            // 24 words
  float* out = (float*)d_out;

  hist_kernel<<<dim3(NBLK), dim3(256), 0, stream>>>(targ, pred, g_part);
  klfused_kernel<<<dim3(NPAIR + 1), dim3(256), 0, stream>>>(g_part, fl1, fl2, out);
}